// Round 9
// baseline (550.667 us; speedup 1.0000x reference)
//
#include <hip/hip_runtime.h>
#include <hip/hip_bf16.h>

#define NP   19
#define EPB  16
#define BLK  256
#define RSTRIDE 4864

// Compact XOR-swizzled LDS layout (single-path staging, round 9):
//   s_Wa rows: 256 shorts (512B, pow2) -> 3-bit key (e&7)<<3 on short index
//   s_tB rows: 160 shorts (320B, 10 o-chunks) -> 2-bit key (e&3)<<3
#define ESA  256           // Wa e-stride (shorts)
#define WAS  (16*ESA)      // Wa total (one path live at a time)
#define ESB  160           // tB e-stride (shorts)
#define TBS  (16*ESB)      // tB total (one path live)
#define CGS  392           // s_cgy16 e-stride (shorts); 784B rows, 16B-aligned.
// LDS: Wa 8192 ; tB 5632 (incl 512B overrun pad) ; cgy16 12544 ; dest/nn 128
//   -> 26496 B -> 6 blocks/CU (was 39936 -> 4). __launch_bounds__ min stays 4;
//   HW fills to 6 since VGPR=60 and LDS now allow it (min is not a max).
// Round-1 lesson: asking min=5 crushes VGPRs -> scratch spill. Keep 4.
// Round-6: full unroll (357us). Round-7 lesson: per-element device atomics =
// RMW at the cross-XCD coherent point (406MB). Round-8: CSR + block-segmented
// reduction (WRITE 21MB). Round-9: single-path staging; MFMA-2 runs 16x16x32
// with the upper K-half zero-masked (q>=2 lanes feed zero frags) -- trades
// wasted MFMA throughput (MfmaUtil was 13%) for 13.4KB of LDS -> occupancy.
#define MINBPC 4

typedef __attribute__((ext_vector_type(8))) short bf16x8;
typedef __attribute__((ext_vector_type(4))) float f32x4;

// ---- per-path metadata (compile-time after full unroll) ----
__device__ const int   d_io[NP]  = {0,0,0, 1,1,1,1,1,1,1, 2,2,2,2, 2,2,2,2,2};
__device__ const int   d_ii[NP]  = {0,1,2, 0,1,1,1,2,2,2, 0,1,1,1, 2,2,2,2,2};
__device__ const int   d_lf[NP]  = {0,1,2, 1,0,1,2,1,2,3, 2,1,2,3, 0,1,2,3,4};
__device__ const int   d_cgb[NP] = {0,1,10, 35,44,53,80,125,170,245, 350,375,420,495, 600,625,700,825,1000};
// s_cgy16 per-path base (shorts). Non-overlapping packing, total 389 <= CGS=392:
//   dI=5: p2@0(8) p7@8(24) p8@32(24) p9@56(24) p14@80(40) p15@120(40)
//         p16@160(40) p17@200(40) p18@240(40)
//   dI=3: p1@280(4) p4@284(12) p5@296(12) p6@308(12) p11@320(20) p12@340(20) p13@360(20)
//   dI=1: p0@380(1) p3@381(3) p10@384(5)
__device__ const int   d_cgyb[NP] = {380,280,0, 381,284,296,308, 8,32,56, 384,320,340,360, 80,120,160,200,240};
__device__ const float d_nrm5[5] = {1.0f, 0.57735026918962576f, 0.44721359549995794f,
                                    0.37796447300922722f, 0.33333333333333333f};

__device__ __forceinline__ unsigned short to_bf16(float v) {
    __hip_bfloat16 h = __float2bfloat16(v);
    return *reinterpret_cast<unsigned short*>(&h);
}
__device__ __forceinline__ float bf2f(unsigned short u) {
    unsigned int x = ((unsigned int)u) << 16;
    union { unsigned int i; float f; } c; c.i = x;
    return c.f;
}

// ---- setup: swizzle R into MFMA fragment order, bf16, K 10->32 zero-padded ----
__global__ void k_rt(const float* __restrict__ R, unsigned short* __restrict__ Rt) {
    int i = blockIdx.x * blockDim.x + threadIdx.x;     // over NP*16*64*8
    if (i >= NP * 16 * 64 * 8) return;
    const int j    = i & 7;
    const int lane = (i >> 3) & 63;
    const int t    = (i >> 9) & 15;
    const int p    = i >> 13;
    const int r    = (lane >> 4) * 8 + j;
    const int col  = p * 256 + 16 * t + (lane & 15);
    float v = (r < 10) ? R[r * RSTRIDE + col] : 0.f;
    Rt[i] = to_bf16(v);
}

// ---------------- Fused: CSR-ordered edges, MFMA pipeline, block-reduced scatter ----------------
__global__ __launch_bounds__(BLK, MINBPC)
void se3_msg(const float* __restrict__ F,
             const float* __restrict__ Ys, const float* __restrict__ Rad,
             const float* __restrict__ cg, const unsigned short* __restrict__ Rt,
             const int* __restrict__ Mb, const int* __restrict__ Ma,
             const int* __restrict__ eidx, const float* __restrict__ Nn,
             float* __restrict__ Out, const int nE)
{
    __shared__ __align__(16) unsigned short s_Wa[WAS];             // Wstack A-frag (single path)
    __shared__ __align__(16) unsigned short s_tB[TBS + 256];       // tmpstack B-frag (single path) + overrun pad
    __shared__ __align__(16) unsigned short s_cgy16[EPB * CGS];    // precomputed cgY; aliased as f32 scratch in epilogue
    __shared__ int   s_dest[EPB];                                  // dest node per edge slot (-1 = inactive)
    __shared__ float s_nn[EPB];                                    // n_norm per edge slot

    const int tid  = threadIdx.x;
    const int l    = tid & 15;
    const int eloc = tid >> 4;
    const int lane = tid & 63;
    const int wv   = tid >> 6;
    const int q    = lane >> 4;
    const int n16  = lane & 15;
    const int slot = blockIdx.x * EPB + eloc;
    const bool act = (slot < nE);
    const int  es  = act ? eidx[slot] : 0;       // CSR-ordered edge id

    // dest + n_norm per slot (early issue; random 2-chain hidden under prologue)
    if (tid < EPB) {
        const int sl = blockIdx.x * EPB + tid;
        int a = -1; float nn = 0.f;
        if (sl < nE) { a = Ma[eidx[sl]]; nn = Nn[a]; }
        s_dest[tid] = a; s_nn[tid] = nn;
    }

    // F slice -> registers (compile-time indexed)
    float fv[9];
    {
        const int b = Mb[es];
        const float* Fb = F + (size_t)b * 144;
        fv[0] = Fb[l];
        #pragma unroll
        for (int i = 0; i < 3; ++i) fv[1 + i] = Fb[16 + l*3 + i];
        #pragma unroll
        for (int i = 0; i < 5; ++i) fv[4 + i] = Fb[64 + l*5 + i];
    }
    // Ys row -> registers (dead after cgY prologue)
    float y[25];
    {
        const float* yr = Ys + (size_t)es * 25;
        #pragma unroll
        for (int k = 0; k < 25; ++k) y[k] = yr[k];
    }
    // radii fragment (B operand of MFMA-1): B[k=r][n=e], K zero-padded 10->32
    bf16x8 radfrag;
    {
        const int k0 = q * 8;
        const int gslot = blockIdx.x * EPB + n16;
        const bool a = (gslot < nE);
        const int  ge = a ? eidx[gslot] : 0;
        const float* rp = Rad + (size_t)ge * 10;
        #pragma unroll
        for (int j = 0; j < 8; ++j) {
            const int k = k0 + j;
            radfrag[j] = (short)((a && k < 10) ? to_bf16(rp[k]) : (unsigned short)0);
        }
    }

    const int keyB = (eloc & 3) << 3;      // tB swizzle key for our row
    const int rowB = eloc * ESB;

    // tb one-time zero; 10 used chunks (row 9 stays zero forever)
    {
        #pragma unroll
        for (int n = 0; n < 10; ++n) {
            const int off = (rowB + (n << 4) + l) ^ keyB;
            s_tB[off] = 0;
        }
    }

    // ---- PROLOGUE: precompute ALL cgY (19 paths) into s_cgy16, bf16 compact ----
    {
        #pragma unroll
        for (int p = 0; p < NP; ++p) {
            const int io = d_io[p], ii = d_ii[p], lf = d_lf[p];
            const int cgb = d_cgb[p], cb = d_cgyb[p];
            const int dO = 2*io + 1, dI = 2*ii + 1, dF = 2*lf + 1;
            const int nOI = dO * dI;
            const float nrm = d_nrm5[lf];
            #pragma unroll
            for (int jj = 0; jj < 2; ++jj) {
                const int j = l + 16*jj;
                if (j < nOI) {            // pruned at compile time when nOI <= 16*jj
                    const int o = j / dI, i = j - o*dI;
                    const float* cgp = cg + cgb + j*dF;
                    float s = 0.f;
                    #pragma unroll
                    for (int f = 0; f < dF; ++f) s += cgp[f] * y[lf*lf + f];
                    const int off = (dI == 1) ? o : (dI == 3) ? (o*4 + i) : (o*8 + i);
                    s_cgy16[eloc*CGS + cb + off] = to_bf16(s * nrm);
                }
            }
        }
    }
    __asm__ volatile("" ::: "memory");   // cgY visible (intra-wave, DS in-order)

    // Rt prefetch double-buffer: rf[p&1] holds path p's 4 fragments
    bf16x8 rf[2][4];
    {
        const unsigned short* r0 = Rt + (size_t)(4*wv)*512 + lane*8;
        #pragma unroll
        for (int tt = 0; tt < 4; ++tt) rf[0][tt] = *reinterpret_cast<const bf16x8*>(r0 + tt*512);
    }

    f32x4 D[4];
    #pragma unroll
    for (int ee = 0; ee < 4; ++ee) D[ee] = (f32x4){0.f,0.f,0.f,0.f};

    // ---- K-loop: FULLY UNROLLED over 19 paths; single-path staging.
    // Per path: stage W_p (MFMA-1) + tmp_p -> barrier -> masked-K MFMA-2 -> barrier.
    #pragma unroll
    for (int p = 0; p < NP; ++p) {
        // prefetch next path's Rt fragments into the other buffer
        if (p + 1 < NP) {
            const unsigned short* rn = Rt + (size_t)(p+1)*8192 + (size_t)(4*wv)*512 + lane*8;
            #pragma unroll
            for (int tt = 0; tt < 4; ++tt)
                rf[(p & 1) ^ 1][tt] = *reinterpret_cast<const bf16x8*>(rn + tt*512);
        }

        // MFMA-1 (swapped): D = R_p^T(16c x 32k) @ rad^T(32k x 16e)
        #pragma unroll
        for (int tt = 0; tt < 4; ++tt) {
            f32x4 d = __builtin_amdgcn_mfma_f32_16x16x32_bf16(
                          rf[p & 1][tt], radfrag, (f32x4){0.f,0.f,0.f,0.f}, 0, 0, 0);
            short4 pk;
            pk.x = (short)to_bf16(d[0]); pk.y = (short)to_bf16(d[1]);
            pk.z = (short)to_bf16(d[2]); pk.w = (short)to_bf16(d[3]);
            const int w = 4*wv + tt;
            *reinterpret_cast<short4*>(
                &s_Wa[(((n16 << 8) + (w << 4) + (q << 2)) ^ ((n16 & 7) << 3))]) = pk;
        }

        // path metadata (compile-time constants after unroll)
        const int io = d_io[p], ii = d_ii[p], cb = d_cgyb[p];
        const int dO = 2*io + 1;
        const int ob  = (io == 0) ? 0 : (io == 1) ? 1 : 4;

        // tmp stale-row zeroing: path row-sets are monotone (p0-2: {0};
        // p3-9: {1-3}; p10-18: {4-8}); zero only at the two transitions.
        const unsigned short* cgw = &s_cgy16[eloc*CGS + cb];
        unsigned short* tbh = s_tB;
        if (p == 3)       { tbh[(rowB + l) ^ keyB] = 0; }
        else if (p == 10) { tbh[(rowB + 16 + l) ^ keyB] = 0;
                            tbh[(rowB + 32 + l) ^ keyB] = 0;
                            tbh[(rowB + 48 + l) ^ keyB] = 0; }
        if (ii == 0) {
            #pragma unroll
            for (int o = 0; o < dO; ++o) {
                const float c0 = bf2f(cgw[o]);
                tbh[(rowB + ((ob + o) << 4) + l) ^ keyB] = to_bf16(fv[0]*c0);
            }
        } else if (ii == 1) {
            #pragma unroll
            for (int o = 0; o < dO; ++o) {
                const short4 c = *reinterpret_cast<const short4*>(&cgw[o*4]);
                tbh[(rowB + ((ob + o) << 4) + l) ^ keyB] =
                    to_bf16(fv[1]*bf2f((unsigned short)c.x)
                          + fv[2]*bf2f((unsigned short)c.y)
                          + fv[3]*bf2f((unsigned short)c.z));
            }
        } else {
            #pragma unroll
            for (int o = 0; o < dO; ++o) {
                const bf16x8 c = *reinterpret_cast<const bf16x8*>(&cgw[o*8]);
                tbh[(rowB + ((ob + o) << 4) + l) ^ keyB] =
                    to_bf16(fv[4]*bf2f((unsigned short)c[0])
                          + fv[5]*bf2f((unsigned short)c[1])
                          + fv[6]*bf2f((unsigned short)c[2])
                          + fv[7]*bf2f((unsigned short)c[3])
                          + fv[8]*bf2f((unsigned short)c[4]));
            }
        }

        __syncthreads();   // W + tmp staged for this path

        // MFMA-2 K-step (masked upper half): msg_e += W_e(16x16) @ tmp_e(16x16)
        // via 16x16x32 with k=16..31 fed zeros (lanes q>=2 supply zero frags).
        {
            const bf16x8 zero8 = {0,0,0,0,0,0,0,0};
            #pragma unroll
            for (int ee = 0; ee < 4; ++ee) {
                const int eK = 4*wv + ee;
                bf16x8 Af = zero8, Bf = zero8;
                if (q < 2) {
                    Af = *reinterpret_cast<const bf16x8*>(
                        &s_Wa[(((eK << 8) + (n16 << 4) + (q << 3)) ^ ((eK & 7) << 3))]);
                    Bf = *reinterpret_cast<const bf16x8*>(
                        &s_tB[((eK*ESB + (n16 << 4) + (q << 3)) ^ ((eK & 3) << 3))]);
                }
                D[ee] = __builtin_amdgcn_mfma_f32_16x16x32_bf16(Af, Bf, D[ee], 0, 0, 0);
            }
        }
        __syncthreads();   // WAR: next path rewrites s_Wa / s_tB
    }

    // ---- FUSED EPILOGUE: block-level segmented reduction by destination, then
    // one atomicAdd per (distinct dest x element). s_cgy16 (dead) aliased as
    // f32 scratch: 16 slots x 160 f32 = 10240 B <= 12544 B.
    float* sred = reinterpret_cast<float*>(s_cgy16);
    if (n16 < 9) {
        #pragma unroll
        for (int ee = 0; ee < 4; ++ee) {
            float4 v4; v4.x = D[ee][0]; v4.y = D[ee][1]; v4.z = D[ee][2]; v4.w = D[ee][3];
            *reinterpret_cast<float4*>(&sred[(4*wv + ee)*160 + n16*16 + q*4]) = v4;
        }
    }
    __syncthreads();

    if (tid < 144) {
        const int w  = tid & 15;          // mul index
        const int of = tid >> 4;          // oflat 0..8
        // proven Out mapping (round 7): of==0 -> w ; 1..3 -> 16+w*3+(of-1) ; 4..8 -> 64+w*5+(of-4)
        const int oidx = (of == 0) ? w : (of <= 3) ? (16 + w*3 + (of - 1)) : (64 + w*5 + (of - 4));
        const int col = of*16 + w;
        int i = 0;
        while (i < EPB) {
            const int a = s_dest[i];
            if (a < 0) { ++i; continue; }
            float s = 0.f;
            int j = i;
            do { s += sred[j*160 + col]; ++j; } while (j < EPB && s_dest[j] == a);
            atomicAdd(&Out[(size_t)a * 144 + oidx], s * s_nn[i]);
            i = j;
        }
    }
}

// ---------------- CSR build (by destination) ----------------
__global__ void k_count(const int* __restrict__ Ma, int* __restrict__ cur, int E) {
    int e = blockIdx.x * blockDim.x + threadIdx.x;
    if (e < E) atomicAdd(&cur[Ma[e]], 1);
}

__global__ void k_scan(int* __restrict__ cur, int* __restrict__ off, int N) {
    __shared__ int part[BLK];
    const int t = threadIdx.x;
    const int K = (N + BLK - 1) / BLK;
    const int i0 = t * K, i1 = min(i0 + K, N);
    int s = 0;
    for (int i = i0; i < i1; ++i) s += cur[i];
    part[t] = s;
    __syncthreads();
    if (t == 0) {
        int a = 0;
        for (int j = 0; j < BLK; ++j) { int v = part[j]; part[j] = a; a += v; }
        off[N] = a;
    }
    __syncthreads();
    int a = part[t];
    for (int i = i0; i < i1; ++i) {
        int v = cur[i];
        off[i] = a;
        cur[i] = a;       // reuse as scatter cursor
        a += v;
    }
}

__global__ void k_scatter(const int* __restrict__ Ma, int* __restrict__ cur,
                          int* __restrict__ eidx, int E) {
    int e = blockIdx.x * blockDim.x + threadIdx.x;
    if (e < E) {
        int pos = atomicAdd(&cur[Ma[e]], 1);
        eidx[pos] = e;
    }
}

extern "C" void kernel_launch(void* const* d_in, const int* in_sizes, int n_in,
                              void* d_out, int out_size, void* d_ws, size_t ws_size,
                              hipStream_t stream) {
    const float* F   = (const float*)d_in[0];
    const float* R   = (const float*)d_in[1];
    const float* Ys  = (const float*)d_in[2];
    const float* Rad = (const float*)d_in[3];
    const float* cg  = (const float*)d_in[4];
    const float* Nn  = (const float*)d_in[5];
    const int*   Ma  = (const int*)d_in[6];
    const int*   Mb  = (const int*)d_in[7];
    float* Out = (float*)d_out;

    const int nE = in_sizes[6];   // edges
    const int nN = in_sizes[5];   // nodes

    // ws layout: [cur nN][off nN+1][eidx nE][pad][Rt NP*16*64*8 bf16]
    int* wsI  = (int*)d_ws;
    int* cur  = wsI;
    int* off  = wsI + nN;
    int* eidx = wsI + 2*nN + 1;
    size_t rtOff = ((size_t)(2*nN + 1 + nE) + 63) & ~(size_t)63;
    unsigned short* Rt = (unsigned short*)((float*)d_ws + rtOff);

    hipMemsetAsync(cur, 0, (size_t)nN * sizeof(int), stream);
    hipMemsetAsync(Out, 0, (size_t)nN * 144 * sizeof(float), stream);
    k_count  <<<(nE + BLK - 1) / BLK, BLK, 0, stream>>>(Ma, cur, nE);
    k_scan   <<<1, BLK, 0, stream>>>(cur, off, nN);
    k_scatter<<<(nE + BLK - 1) / BLK, BLK, 0, stream>>>(Ma, cur, eidx, nE);
    k_rt     <<<(NP*16*64*8 + BLK - 1) / BLK, BLK, 0, stream>>>(R, Rt);

    se3_msg<<<(nE + EPB - 1) / EPB, BLK, 0, stream>>>(F, Ys, Rad, cg, Rt, Mb, Ma, eidx, Nn, Out, nE);
}

// Round 10
// 505.128 us; speedup vs baseline: 1.0902x; 1.0902x over previous
//
#include <hip/hip_runtime.h>
#include <hip/hip_bf16.h>

#define NP   19
#define EPB  16
#define BLK  256
#define RSTRIDE 4864

// Compact XOR-swizzled LDS layout (round-8 core, frozen):
//   s_Wa rows: 256 shorts (512B, pow2) -> 3-bit key (e&7)<<3 on short index
//   s_tB rows: 160 shorts (320B, 10 o-chunks) -> 2-bit key (e&3)<<3
#define ESA  256           // Wa e-stride (shorts)
#define PBSA (16*ESA)      // Wa K-half stride
#define ESB  160           // tB e-stride (shorts)
#define PBSB (16*ESB)      // tB K-half stride
#define CGS  392           // s_cgy16 e-stride (shorts); 784B rows, 16B-aligned.
// LDS: Wa 16384 ; tB 10752 ; cgy16 12544 ; dest/nn 128 -> 39808 B -> 4 blocks/CU.
// Round-9 lesson: shrinking LDS to 26.6KB did NOT raise residency past 4
// blocks/CU (occupancy flat at 44.7) and the masked-K single-path MFMA-2 cost
// +68us in VALU/barriers -> reverted to the round-8 two-half K=32 structure.
// Round-1 lesson: __launch_bounds__ min=5 crushes VGPRs -> scratch spill. Keep 4.
// Round-7 lesson: per-element device atomics RMW at the cross-XCD coherent
// point (406MB). Round-8: CSR + block-segmented reduction (WRITE 21MB).
// Round-10: k_pg pre-gathers Ys/Rad/Mb/Ma/Nn into CSR-slot order -> se3_msg
// prologue is chain-free and coalesced (round-8's +37us indirection removed).
#define MINBPC 4

typedef __attribute__((ext_vector_type(8))) short bf16x8;
typedef __attribute__((ext_vector_type(4))) float f32x4;

// ---- per-path metadata (compile-time after full unroll) ----
__device__ const int   d_io[NP]  = {0,0,0, 1,1,1,1,1,1,1, 2,2,2,2, 2,2,2,2,2};
__device__ const int   d_ii[NP]  = {0,1,2, 0,1,1,1,2,2,2, 0,1,1,1, 2,2,2,2,2};
__device__ const int   d_lf[NP]  = {0,1,2, 1,0,1,2,1,2,3, 2,1,2,3, 0,1,2,3,4};
__device__ const int   d_cgb[NP] = {0,1,10, 35,44,53,80,125,170,245, 350,375,420,495, 600,625,700,825,1000};
// s_cgy16 per-path base (shorts). Non-overlapping packing, total 389 <= CGS=392:
//   dI=5: p2@0(8) p7@8(24) p8@32(24) p9@56(24) p14@80(40) p15@120(40)
//         p16@160(40) p17@200(40) p18@240(40)
//   dI=3: p1@280(4) p4@284(12) p5@296(12) p6@308(12) p11@320(20) p12@340(20) p13@360(20)
//   dI=1: p0@380(1) p3@381(3) p10@384(5)
__device__ const int   d_cgyb[NP] = {380,280,0, 381,284,296,308, 8,32,56, 384,320,340,360, 80,120,160,200,240};
__device__ const float d_nrm5[5] = {1.0f, 0.57735026918962576f, 0.44721359549995794f,
                                    0.37796447300922722f, 0.33333333333333333f};

__device__ __forceinline__ unsigned short to_bf16(float v) {
    __hip_bfloat16 h = __float2bfloat16(v);
    return *reinterpret_cast<unsigned short*>(&h);
}
__device__ __forceinline__ float bf2f(unsigned short u) {
    unsigned int x = ((unsigned int)u) << 16;
    union { unsigned int i; float f; } c; c.i = x;
    return c.f;
}

// ---- setup: swizzle R into MFMA fragment order, bf16, K 10->32 zero-padded ----
__global__ void k_rt(const float* __restrict__ R, unsigned short* __restrict__ Rt) {
    int i = blockIdx.x * blockDim.x + threadIdx.x;     // over NP*16*64*8
    if (i >= NP * 16 * 64 * 8) return;
    const int j    = i & 7;
    const int lane = (i >> 3) & 63;
    const int t    = (i >> 9) & 15;
    const int p    = i >> 13;
    const int r    = (lane >> 4) * 8 + j;
    const int col  = p * 256 + 16 * t + (lane & 15);
    float v = (r < 10) ? R[r * RSTRIDE + col] : 0.f;
    Rt[i] = to_bf16(v);
}

// ---- pre-gather: materialize per-edge inputs in CSR-slot order (coalesced
// consumption in se3_msg; removes the eidx load chain + partial-line fetches) ----
__global__ void k_pg(const float* __restrict__ Ys, const float* __restrict__ Rad,
                     const int* __restrict__ Mb, const int* __restrict__ Ma,
                     const float* __restrict__ Nn, const int* __restrict__ eidx,
                     float* __restrict__ YRg, int* __restrict__ Mbg,
                     int* __restrict__ destg, float* __restrict__ nng, const int nE) {
    const int slot = blockIdx.x * BLK + threadIdx.x;
    if (slot >= nE) return;
    const int e = eidx[slot];
    const float* ys = Ys + (size_t)e * 25;
    const float* rd = Rad + (size_t)e * 10;
    float* o = YRg + (size_t)slot * 36;
    #pragma unroll
    for (int k = 0; k < 25; ++k) o[k] = ys[k];
    #pragma unroll
    for (int k = 0; k < 10; ++k) o[25 + k] = rd[k];
    o[35] = 0.f;
    Mbg[slot] = Mb[e];
    const int a = Ma[e];
    destg[slot] = a;
    nng[slot] = Nn[a];
}

// ---------------- Fused: slot-ordered edges, MFMA pipeline, block-reduced scatter ----------------
__global__ __launch_bounds__(BLK, MINBPC)
void se3_msg(const float* __restrict__ F, const float* __restrict__ YRg,
             const float* __restrict__ cg, const unsigned short* __restrict__ Rt,
             const int* __restrict__ Mbg, const int* __restrict__ destg,
             const float* __restrict__ nng,
             float* __restrict__ Out, const int nE)
{
    __shared__ __align__(16) unsigned short s_Wa[2 * PBSA];        // Wstack A-frag (two K-halves)
    __shared__ __align__(16) unsigned short s_tB[2 * PBSB + 256];  // tmpstack B-frag + overrun pad
    __shared__ __align__(16) unsigned short s_cgy16[EPB * CGS];    // precomputed cgY; f32 scratch in epilogue
    __shared__ int   s_dest[EPB];                                  // dest node per edge slot (-1 = inactive)
    __shared__ float s_nn[EPB];                                    // n_norm per edge slot

    const int tid  = threadIdx.x;
    const int l    = tid & 15;
    const int eloc = tid >> 4;
    const int lane = tid & 63;
    const int wv   = tid >> 6;
    const int q    = lane >> 4;
    const int n16  = lane & 15;
    const int slot = blockIdx.x * EPB + eloc;
    const bool act = (slot < nE);
    const int  es  = act ? slot : 0;             // direct slot index (pre-gathered)

    // dest + n_norm per slot (coalesced from pre-gathered arrays)
    if (tid < EPB) {
        const int sl = blockIdx.x * EPB + tid;
        int a = -1; float nn = 0.f;
        if (sl < nE) { a = destg[sl]; nn = nng[sl]; }
        s_dest[tid] = a; s_nn[tid] = nn;
    }

    // F slice -> registers (compile-time indexed)
    float fv[9];
    {
        const int b = Mbg[es];
        const float* Fb = F + (size_t)b * 144;
        fv[0] = Fb[l];
        #pragma unroll
        for (int i = 0; i < 3; ++i) fv[1 + i] = Fb[16 + l*3 + i];
        #pragma unroll
        for (int i = 0; i < 5; ++i) fv[4 + i] = Fb[64 + l*5 + i];
    }
    // Ys row -> registers (dead after cgY prologue)
    float y[25];
    {
        const float* yr = YRg + (size_t)es * 36;
        #pragma unroll
        for (int k = 0; k < 25; ++k) y[k] = yr[k];
    }
    // radii fragment (B operand of MFMA-1): B[k=r][n=e], K zero-padded 10->32
    bf16x8 radfrag;
    {
        const int k0 = q * 8;
        const int gslot = blockIdx.x * EPB + n16;
        const bool a = (gslot < nE);
        const float* rp = YRg + (size_t)(a ? gslot : 0) * 36 + 25;
        #pragma unroll
        for (int j = 0; j < 8; ++j) {
            const int k = k0 + j;
            radfrag[j] = (short)((a && k < 10) ? to_bf16(rp[k]) : (unsigned short)0);
        }
    }

    const int keyB = (eloc & 3) << 3;      // tB swizzle key for our row
    const int rowB = eloc * ESB;

    // tb one-time zero (maintained incrementally afterwards); 10 used chunks
    {
        #pragma unroll
        for (int n = 0; n < 10; ++n) {
            const int off = (rowB + (n << 4) + l) ^ keyB;
            s_tB[off] = 0; s_tB[PBSB + off] = 0;
        }
    }

    // ---- PROLOGUE: precompute ALL cgY (19 paths) into s_cgy16, bf16 compact ----
    {
        #pragma unroll
        for (int p = 0; p < NP; ++p) {
            const int io = d_io[p], ii = d_ii[p], lf = d_lf[p];
            const int cgb = d_cgb[p], cb = d_cgyb[p];
            const int dO = 2*io + 1, dI = 2*ii + 1, dF = 2*lf + 1;
            const int nOI = dO * dI;
            const float nrm = d_nrm5[lf];
            #pragma unroll
            for (int jj = 0; jj < 2; ++jj) {
                const int j = l + 16*jj;
                if (j < nOI) {            // pruned at compile time when nOI <= 16*jj
                    const int o = j / dI, i = j - o*dI;
                    const float* cgp = cg + cgb + j*dF;
                    float s = 0.f;
                    #pragma unroll
                    for (int f = 0; f < dF; ++f) s += cgp[f] * y[lf*lf + f];
                    const int off = (dI == 1) ? o : (dI == 3) ? (o*4 + i) : (o*8 + i);
                    s_cgy16[eloc*CGS + cb + off] = to_bf16(s * nrm);
                }
            }
        }
    }
    __asm__ volatile("" ::: "memory");   // cgY visible (intra-wave, DS in-order)

    // Rt prefetch double-buffer: rf[pb] holds path p's 4 fragments
    bf16x8 rf[2][4];
    {
        const unsigned short* r0 = Rt + (size_t)(4*wv)*512 + lane*8;
        #pragma unroll
        for (int tt = 0; tt < 4; ++tt) rf[0][tt] = *reinterpret_cast<const bf16x8*>(r0 + tt*512);
    }

    f32x4 D[4];
    #pragma unroll
    for (int ee = 0; ee < 4; ++ee) D[ee] = (f32x4){0.f,0.f,0.f,0.f};

    // ---- K-block loop: FULLY UNROLLED. 10 x (2 paths staged -> 1 MFMA-2 K-step).
    #pragma unroll
    for (int kb = 0; kb < 10; ++kb) {
        #pragma unroll
        for (int pb = 0; pb < 2; ++pb) {
            const int p = 2*kb + pb;
            // prefetch next path's Rt fragments into the other buffer
            if (p + 1 < NP) {
                const unsigned short* rn = Rt + (size_t)(p+1)*8192 + (size_t)(4*wv)*512 + lane*8;
                #pragma unroll
                for (int tt = 0; tt < 4; ++tt)
                    rf[pb ^ 1][tt] = *reinterpret_cast<const bf16x8*>(rn + tt*512);
            }
            if (p < NP) {
                // MFMA-1 (swapped): D = R_p^T(16c x 32k) @ rad^T(32k x 16e)
                #pragma unroll
                for (int tt = 0; tt < 4; ++tt) {
                    f32x4 d = __builtin_amdgcn_mfma_f32_16x16x32_bf16(
                                  rf[pb][tt], radfrag, (f32x4){0.f,0.f,0.f,0.f}, 0, 0, 0);
                    short4 pk;
                    pk.x = (short)to_bf16(d[0]); pk.y = (short)to_bf16(d[1]);
                    pk.z = (short)to_bf16(d[2]); pk.w = (short)to_bf16(d[3]);
                    const int w = 4*wv + tt;
                    *reinterpret_cast<short4*>(
                        &s_Wa[pb*PBSA + (((n16 << 8) + (w << 4) + (q << 2)) ^ ((n16 & 7) << 3))]) = pk;
                }

                // path metadata (compile-time constants after unroll)
                const int io = d_io[p], ii = d_ii[p], cb = d_cgyb[p];
                const int dO = 2*io + 1;
                const int ob  = (io == 0) ? 0 : (io == 1) ? 1 : 4;

                // tmp[v=l, o] -> B-frag bf16 [e][n=ob+o][v]; zero only vacated slots.
                const unsigned short* cgw = &s_cgy16[eloc*CGS + cb];
                unsigned short* tbh = &s_tB[pb*PBSB];
                if (p == 3 || p == 4)        { tbh[(rowB + l) ^ keyB] = 0; }
                else if (p == 10 || p == 11) { tbh[(rowB + 16 + l) ^ keyB] = 0;
                                               tbh[(rowB + 32 + l) ^ keyB] = 0;
                                               tbh[(rowB + 48 + l) ^ keyB] = 0; }
                if (ii == 0) {
                    #pragma unroll
                    for (int o = 0; o < dO; ++o) {
                        const float c0 = bf2f(cgw[o]);
                        tbh[(rowB + ((ob + o) << 4) + l) ^ keyB] = to_bf16(fv[0]*c0);
                    }
                } else if (ii == 1) {
                    #pragma unroll
                    for (int o = 0; o < dO; ++o) {
                        const short4 c = *reinterpret_cast<const short4*>(&cgw[o*4]);
                        tbh[(rowB + ((ob + o) << 4) + l) ^ keyB] =
                            to_bf16(fv[1]*bf2f((unsigned short)c.x)
                                  + fv[2]*bf2f((unsigned short)c.y)
                                  + fv[3]*bf2f((unsigned short)c.z));
                    }
                } else {
                    #pragma unroll
                    for (int o = 0; o < dO; ++o) {
                        const bf16x8 c = *reinterpret_cast<const bf16x8*>(&cgw[o*8]);
                        tbh[(rowB + ((ob + o) << 4) + l) ^ keyB] =
                            to_bf16(fv[4]*bf2f((unsigned short)c[0])
                                  + fv[5]*bf2f((unsigned short)c[1])
                                  + fv[6]*bf2f((unsigned short)c[2])
                                  + fv[7]*bf2f((unsigned short)c[3])
                                  + fv[8]*bf2f((unsigned short)c[4]));
                    }
                }
            } else {
                // p == 19 pad: zero our W slots (A==0 kills stale tb of this K-half)
                const short4 z = {0, 0, 0, 0};
                #pragma unroll
                for (int tt = 0; tt < 4; ++tt) {
                    const int w = 4*wv + tt;
                    *reinterpret_cast<short4*>(
                        &s_Wa[pb*PBSA + (((n16 << 8) + (w << 4) + (q << 2)) ^ ((n16 & 7) << 3))]) = z;
                }
            }
        }
        __syncthreads();   // W (cross-wave w-tiles) staged for this K-block

        // MFMA-2 K-step: msg_e(16w x 16n) += Wstack_e(16x32) @ tmpstack_e(32x16)
        {
            const int kh = q >> 1;
            const int vh = (q & 1) << 3;
            #pragma unroll
            for (int ee = 0; ee < 4; ++ee) {
                const int eK   = 4*wv + ee;
                const bf16x8 Af = *reinterpret_cast<const bf16x8*>(
                    &s_Wa[kh*PBSA + (((eK << 8) + (n16 << 4) + vh) ^ ((eK & 7) << 3))]);
                const bf16x8 Bf = *reinterpret_cast<const bf16x8*>(
                    &s_tB[kh*PBSB + ((eK*ESB + (n16 << 4) + vh) ^ ((eK & 3) << 3))]);
                D[ee] = __builtin_amdgcn_mfma_f32_16x16x32_bf16(Af, Bf, D[ee], 0, 0, 0);
            }
        }
        __syncthreads();   // WAR: next K-block rewrites s_Wa / s_tB
    }

    // ---- FUSED EPILOGUE: block-level segmented reduction by destination, then
    // one atomicAdd per (distinct dest x element). s_cgy16 (dead) aliased as
    // f32 scratch: 16 slots x 160 f32 = 10240 B <= 12544 B.
    float* sred = reinterpret_cast<float*>(s_cgy16);
    __syncthreads();   // all cgY reads done before aliasing
    if (n16 < 9) {
        #pragma unroll
        for (int ee = 0; ee < 4; ++ee) {
            float4 v4; v4.x = D[ee][0]; v4.y = D[ee][1]; v4.z = D[ee][2]; v4.w = D[ee][3];
            *reinterpret_cast<float4*>(&sred[(4*wv + ee)*160 + n16*16 + q*4]) = v4;
        }
    }
    __syncthreads();

    if (tid < 144) {
        const int w  = tid & 15;          // mul index
        const int of = tid >> 4;          // oflat 0..8
        // proven Out mapping (round 7): of==0 -> w ; 1..3 -> 16+w*3+(of-1) ; 4..8 -> 64+w*5+(of-4)
        const int oidx = (of == 0) ? w : (of <= 3) ? (16 + w*3 + (of - 1)) : (64 + w*5 + (of - 4));
        const int col = of*16 + w;
        int i = 0;
        while (i < EPB) {
            const int a = s_dest[i];
            if (a < 0) { ++i; continue; }
            float s = 0.f;
            int j = i;
            do { s += sred[j*160 + col]; ++j; } while (j < EPB && s_dest[j] == a);
            atomicAdd(&Out[(size_t)a * 144 + oidx], s * s_nn[i]);
            i = j;
        }
    }
}

// ---------------- CSR build (by destination) ----------------
__global__ void k_count(const int* __restrict__ Ma, int* __restrict__ cur, int E) {
    int e = blockIdx.x * blockDim.x + threadIdx.x;
    if (e < E) atomicAdd(&cur[Ma[e]], 1);
}

__global__ void k_scan(int* __restrict__ cur, int* __restrict__ off, int N) {
    __shared__ int part[BLK];
    const int t = threadIdx.x;
    const int K = (N + BLK - 1) / BLK;
    const int i0 = t * K, i1 = min(i0 + K, N);
    int s = 0;
    for (int i = i0; i < i1; ++i) s += cur[i];
    part[t] = s;
    __syncthreads();
    if (t == 0) {
        int a = 0;
        for (int j = 0; j < BLK; ++j) { int v = part[j]; part[j] = a; a += v; }
        off[N] = a;
    }
    __syncthreads();
    int a = part[t];
    for (int i = i0; i < i1; ++i) {
        int v = cur[i];
        off[i] = a;
        cur[i] = a;       // reuse as scatter cursor
        a += v;
    }
}

__global__ void k_scatter(const int* __restrict__ Ma, int* __restrict__ cur,
                          int* __restrict__ eidx, int E) {
    int e = blockIdx.x * blockDim.x + threadIdx.x;
    if (e < E) {
        int pos = atomicAdd(&cur[Ma[e]], 1);
        eidx[pos] = e;
    }
}

extern "C" void kernel_launch(void* const* d_in, const int* in_sizes, int n_in,
                              void* d_out, int out_size, void* d_ws, size_t ws_size,
                              hipStream_t stream) {
    const float* F   = (const float*)d_in[0];
    const float* R   = (const float*)d_in[1];
    const float* Ys  = (const float*)d_in[2];
    const float* Rad = (const float*)d_in[3];
    const float* cg  = (const float*)d_in[4];
    const float* Nn  = (const float*)d_in[5];
    const int*   Ma  = (const int*)d_in[6];
    const int*   Mb  = (const int*)d_in[7];
    float* Out = (float*)d_out;

    const int nE = in_sizes[6];   // edges
    const int nN = in_sizes[5];   // nodes

    // ws layout (float units): [cur nN][off nN+1][eidx nE][pad]
    //   [YRg nE*36 f32][Mbg nE][destg nE][nng nE][pad][Rt NP*16*64*8 bf16]
    int* wsI  = (int*)d_ws;
    int* cur  = wsI;
    int* off  = wsI + nN;
    int* eidx = wsI + 2*nN + 1;
    size_t yrOff = ((size_t)(2*nN + 1 + nE) + 63) & ~(size_t)63;
    float* YRg   = (float*)d_ws + yrOff;
    int*   Mbg   = (int*)((float*)d_ws + yrOff + (size_t)nE * 36);
    int*   destg = Mbg + nE;
    float* nng   = (float*)(destg + nE);
    size_t rtOff = ((yrOff + (size_t)nE * 39) + 63) & ~(size_t)63;
    unsigned short* Rt = (unsigned short*)((float*)d_ws + rtOff);

    hipMemsetAsync(cur, 0, (size_t)nN * sizeof(int), stream);
    hipMemsetAsync(Out, 0, (size_t)nN * 144 * sizeof(float), stream);
    k_count  <<<(nE + BLK - 1) / BLK, BLK, 0, stream>>>(Ma, cur, nE);
    k_scan   <<<1, BLK, 0, stream>>>(cur, off, nN);
    k_scatter<<<(nE + BLK - 1) / BLK, BLK, 0, stream>>>(Ma, cur, eidx, nE);
    k_rt     <<<(NP*16*64*8 + BLK - 1) / BLK, BLK, 0, stream>>>(R, Rt);
    k_pg     <<<(nE + BLK - 1) / BLK, BLK, 0, stream>>>(Ys, Rad, Mb, Ma, Nn, eidx,
                                                        YRg, Mbg, destg, nng, nE);

    se3_msg<<<(nE + EPB - 1) / EPB, BLK, 0, stream>>>(F, YRg, cg, Rt, Mbg, destg, nng, Out, nE);
}

// Round 11
// 469.170 us; speedup vs baseline: 1.1737x; 1.0766x over previous
//
#include <hip/hip_runtime.h>
#include <hip/hip_bf16.h>

#define NP   19
#define EPB  16
#define BLK  256
#define RSTRIDE 4864

// Compact XOR-swizzled LDS layout (round-6 core, frozen):
//   s_Wa rows: 256 shorts (512B, pow2) -> 3-bit key (e&7)<<3 on short index
//   s_tB rows: 160 shorts (320B, 10 o-chunks) -> 2-bit key (e&3)<<3
#define ESA  256           // Wa e-stride (shorts)
#define PBSA (16*ESA)      // Wa K-half stride
#define ESB  160           // tB e-stride (shorts)
#define PBSB (16*ESB)      // tB K-half stride
#define CGS  392           // s_cgy16 e-stride (shorts); 784B rows, 16B-aligned.
// LDS: Wa 16384 ; tB 10752 ; cgy16 12544 -> 39680 B -> 4 blocks/CU.
// Ledger of structural lessons:
//  R1: __launch_bounds__ min=5 crushes VGPRs -> 540MB scratch spill. Keep 4.
//  R6: fully-unrolled K-loop, runtime->compile-time path metadata: 357us. BEST.
//  R7: per-element device atomicAdd resolves at the cross-XCD coherent point:
//      36M atomics = +406MB RMW traffic, +257us. Never per-element atomics.
//  R8-R10: fused scatter (CSR + block-segmented reduce + pre-gather) exactly
//      re-spends what it saves (fused total 505 vs two-phase 485). Reverted.
//  R9: LDS 26.6KB did NOT raise residency past 4 blocks/CU; occupancy is not
//      LDS-limited below 40KB. Barriers ~450cy each (18 extra cost 8us/round).
//  R11: msg intermediate in bf16 -- halves the 144MB write + 144MB gather read.
#define MINBPC 4

typedef __attribute__((ext_vector_type(8))) short bf16x8;
typedef __attribute__((ext_vector_type(4))) float f32x4;

// ---- per-path metadata (compile-time after full unroll) ----
__device__ const int   d_io[NP]  = {0,0,0, 1,1,1,1,1,1,1, 2,2,2,2, 2,2,2,2,2};
__device__ const int   d_ii[NP]  = {0,1,2, 0,1,1,1,2,2,2, 0,1,1,1, 2,2,2,2,2};
__device__ const int   d_lf[NP]  = {0,1,2, 1,0,1,2,1,2,3, 2,1,2,3, 0,1,2,3,4};
__device__ const int   d_cgb[NP] = {0,1,10, 35,44,53,80,125,170,245, 350,375,420,495, 600,625,700,825,1000};
// s_cgy16 per-path base (shorts). Non-overlapping packing, total 389 <= CGS=392:
//   dI=5: p2@0(8) p7@8(24) p8@32(24) p9@56(24) p14@80(40) p15@120(40)
//         p16@160(40) p17@200(40) p18@240(40)
//   dI=3: p1@280(4) p4@284(12) p5@296(12) p6@308(12) p11@320(20) p12@340(20) p13@360(20)
//   dI=1: p0@380(1) p3@381(3) p10@384(5)
__device__ const int   d_cgyb[NP] = {380,280,0, 381,284,296,308, 8,32,56, 384,320,340,360, 80,120,160,200,240};
__device__ const float d_nrm5[5] = {1.0f, 0.57735026918962576f, 0.44721359549995794f,
                                    0.37796447300922722f, 0.33333333333333333f};

__device__ __forceinline__ unsigned short to_bf16(float v) {
    __hip_bfloat16 h = __float2bfloat16(v);
    return *reinterpret_cast<unsigned short*>(&h);
}
__device__ __forceinline__ float bf2f(unsigned short u) {
    unsigned int x = ((unsigned int)u) << 16;
    union { unsigned int i; float f; } c; c.i = x;
    return c.f;
}

// ---- fused setup: R swizzle (first RTB blocks) + CSR count (rest) ----
__global__ void k_rtcount(const float* __restrict__ R, unsigned short* __restrict__ Rt,
                          const int* __restrict__ Ma, int* __restrict__ cur, int E) {
    const int RTB = (NP * 16 * 64 * 8) / BLK;      // 608 (exact)
    if ((int)blockIdx.x < RTB) {
        const int i = blockIdx.x * BLK + threadIdx.x;  // over NP*16*64*8
        const int j    = i & 7;
        const int lane = (i >> 3) & 63;
        const int t    = (i >> 9) & 15;
        const int p    = i >> 13;
        const int r    = (lane >> 4) * 8 + j;
        const int col  = p * 256 + 16 * t + (lane & 15);
        float v = (r < 10) ? R[r * RSTRIDE + col] : 0.f;
        Rt[i] = to_bf16(v);
    } else {
        const int e = (blockIdx.x - RTB) * BLK + threadIdx.x;
        if (e < E) atomicAdd(&cur[Ma[e]], 1);
    }
}

// ---------------- Phase A: edge-major; W-GEMM and msg-GEMM both on MFMA ----------------
__global__ __launch_bounds__(BLK, MINBPC)
void se3_msg(const float* __restrict__ F,
             const float* __restrict__ Ys, const float* __restrict__ Rad,
             const float* __restrict__ cg, const unsigned short* __restrict__ Rt,
             const int* __restrict__ Mb,
             unsigned short* __restrict__ msg, const int nE)
{
    __shared__ __align__(16) unsigned short s_Wa[2 * PBSA];        // Wstack A-frag (two K-halves)
    __shared__ __align__(16) unsigned short s_tB[2 * PBSB + 256];  // tmpstack B-frag + overrun pad
    __shared__ __align__(16) unsigned short s_cgy16[EPB * CGS];    // precomputed cgY (bf16 compact)

    const int tid  = threadIdx.x;
    const int l    = tid & 15;
    const int eloc = tid >> 4;
    const int lane = tid & 63;
    const int wv   = tid >> 6;
    const int q    = lane >> 4;
    const int n16  = lane & 15;
    const int e    = blockIdx.x * EPB + eloc;
    const bool act = (e < nE);
    const int  es  = act ? e : 0;

    // F slice -> registers (compile-time indexed)
    float fv[9];
    {
        const int b = Mb[es];
        const float* Fb = F + (size_t)b * 144;
        fv[0] = Fb[l];
        #pragma unroll
        for (int i = 0; i < 3; ++i) fv[1 + i] = Fb[16 + l*3 + i];
        #pragma unroll
        for (int i = 0; i < 5; ++i) fv[4 + i] = Fb[64 + l*5 + i];
    }
    // Ys row -> registers (dead after cgY prologue)
    float y[25];
    {
        const float* yr = Ys + (size_t)es * 25;
        #pragma unroll
        for (int k = 0; k < 25; ++k) y[k] = yr[k];
    }
    // radii fragment (B operand of MFMA-1): B[k=r][n=e], K zero-padded 10->32
    bf16x8 radfrag;
    {
        const int k0 = q * 8;
        const int ge = blockIdx.x * EPB + n16;
        const bool a = (ge < nE);
        const float* rp = Rad + (size_t)(a ? ge : 0) * 10;
        #pragma unroll
        for (int j = 0; j < 8; ++j) {
            const int k = k0 + j;
            radfrag[j] = (short)((a && k < 10) ? to_bf16(rp[k]) : (unsigned short)0);
        }
    }

    const int keyB = (eloc & 3) << 3;      // tB swizzle key for our row
    const int rowB = eloc * ESB;

    // tb one-time zero (maintained incrementally afterwards); 10 used chunks
    {
        #pragma unroll
        for (int n = 0; n < 10; ++n) {
            const int off = (rowB + (n << 4) + l) ^ keyB;
            s_tB[off] = 0; s_tB[PBSB + off] = 0;
        }
    }

    // ---- PROLOGUE: precompute ALL cgY (19 paths) into s_cgy16, bf16 compact ----
    {
        #pragma unroll
        for (int p = 0; p < NP; ++p) {
            const int io = d_io[p], ii = d_ii[p], lf = d_lf[p];
            const int cgb = d_cgb[p], cb = d_cgyb[p];
            const int dO = 2*io + 1, dI = 2*ii + 1, dF = 2*lf + 1;
            const int nOI = dO * dI;
            const float nrm = d_nrm5[lf];
            #pragma unroll
            for (int jj = 0; jj < 2; ++jj) {
                const int j = l + 16*jj;
                if (j < nOI) {            // pruned at compile time when nOI <= 16*jj
                    const int o = j / dI, i = j - o*dI;
                    const float* cgp = cg + cgb + j*dF;
                    float s = 0.f;
                    #pragma unroll
                    for (int f = 0; f < dF; ++f) s += cgp[f] * y[lf*lf + f];
                    const int off = (dI == 1) ? o : (dI == 3) ? (o*4 + i) : (o*8 + i);
                    s_cgy16[eloc*CGS + cb + off] = to_bf16(s * nrm);
                }
            }
        }
    }
    __asm__ volatile("" ::: "memory");   // cgY visible (intra-wave, DS in-order)

    // Rt prefetch double-buffer: rf[pb] holds path p's 4 fragments
    bf16x8 rf[2][4];
    {
        const unsigned short* r0 = Rt + (size_t)(4*wv)*512 + lane*8;
        #pragma unroll
        for (int tt = 0; tt < 4; ++tt) rf[0][tt] = *reinterpret_cast<const bf16x8*>(r0 + tt*512);
    }

    f32x4 D[4];
    #pragma unroll
    for (int ee = 0; ee < 4; ++ee) D[ee] = (f32x4){0.f,0.f,0.f,0.f};

    // ---- K-block loop: FULLY UNROLLED. 10 x (2 paths staged -> 1 MFMA-2 K-step).
    #pragma unroll
    for (int kb = 0; kb < 10; ++kb) {
        #pragma unroll
        for (int pb = 0; pb < 2; ++pb) {
            const int p = 2*kb + pb;
            // prefetch next path's Rt fragments into the other buffer
            if (p + 1 < NP) {
                const unsigned short* rn = Rt + (size_t)(p+1)*8192 + (size_t)(4*wv)*512 + lane*8;
                #pragma unroll
                for (int tt = 0; tt < 4; ++tt)
                    rf[pb ^ 1][tt] = *reinterpret_cast<const bf16x8*>(rn + tt*512);
            }
            if (p < NP) {
                // MFMA-1 (swapped): D = R_p^T(16c x 32k) @ rad^T(32k x 16e)
                #pragma unroll
                for (int tt = 0; tt < 4; ++tt) {
                    f32x4 d = __builtin_amdgcn_mfma_f32_16x16x32_bf16(
                                  rf[pb][tt], radfrag, (f32x4){0.f,0.f,0.f,0.f}, 0, 0, 0);
                    short4 pk;
                    pk.x = (short)to_bf16(d[0]); pk.y = (short)to_bf16(d[1]);
                    pk.z = (short)to_bf16(d[2]); pk.w = (short)to_bf16(d[3]);
                    const int w = 4*wv + tt;
                    *reinterpret_cast<short4*>(
                        &s_Wa[pb*PBSA + (((n16 << 8) + (w << 4) + (q << 2)) ^ ((n16 & 7) << 3))]) = pk;
                }

                // path metadata (compile-time constants after unroll)
                const int io = d_io[p], ii = d_ii[p], cb = d_cgyb[p];
                const int dO = 2*io + 1;
                const int ob  = (io == 0) ? 0 : (io == 1) ? 1 : 4;

                // tmp[v=l, o] -> B-frag bf16 [e][n=ob+o][v]; zero only vacated slots.
                const unsigned short* cgw = &s_cgy16[eloc*CGS + cb];
                unsigned short* tbh = &s_tB[pb*PBSB];
                if (p == 3 || p == 4)        { tbh[(rowB + l) ^ keyB] = 0; }
                else if (p == 10 || p == 11) { tbh[(rowB + 16 + l) ^ keyB] = 0;
                                               tbh[(rowB + 32 + l) ^ keyB] = 0;
                                               tbh[(rowB + 48 + l) ^ keyB] = 0; }
                if (ii == 0) {
                    #pragma unroll
                    for (int o = 0; o < dO; ++o) {
                        const float c0 = bf2f(cgw[o]);
                        tbh[(rowB + ((ob + o) << 4) + l) ^ keyB] = to_bf16(fv[0]*c0);
                    }
                } else if (ii == 1) {
                    #pragma unroll
                    for (int o = 0; o < dO; ++o) {
                        const short4 c = *reinterpret_cast<const short4*>(&cgw[o*4]);
                        tbh[(rowB + ((ob + o) << 4) + l) ^ keyB] =
                            to_bf16(fv[1]*bf2f((unsigned short)c.x)
                                  + fv[2]*bf2f((unsigned short)c.y)
                                  + fv[3]*bf2f((unsigned short)c.z));
                    }
                } else {
                    #pragma unroll
                    for (int o = 0; o < dO; ++o) {
                        const bf16x8 c = *reinterpret_cast<const bf16x8*>(&cgw[o*8]);
                        tbh[(rowB + ((ob + o) << 4) + l) ^ keyB] =
                            to_bf16(fv[4]*bf2f((unsigned short)c[0])
                                  + fv[5]*bf2f((unsigned short)c[1])
                                  + fv[6]*bf2f((unsigned short)c[2])
                                  + fv[7]*bf2f((unsigned short)c[3])
                                  + fv[8]*bf2f((unsigned short)c[4]));
                    }
                }
            } else {
                // p == 19 pad: zero our W slots (A==0 kills stale tb of this K-half)
                const short4 z = {0, 0, 0, 0};
                #pragma unroll
                for (int tt = 0; tt < 4; ++tt) {
                    const int w = 4*wv + tt;
                    *reinterpret_cast<short4*>(
                        &s_Wa[pb*PBSA + (((n16 << 8) + (w << 4) + (q << 2)) ^ ((n16 & 7) << 3))]) = z;
                }
            }
        }
        __syncthreads();   // W (cross-wave w-tiles) staged for this K-block

        // MFMA-2 K-step: msg_e(16w x 16n) += Wstack_e(16x32) @ tmpstack_e(32x16)
        {
            const int kh = q >> 1;
            const int vh = (q & 1) << 3;
            #pragma unroll
            for (int ee = 0; ee < 4; ++ee) {
                const int eK   = 4*wv + ee;
                const bf16x8 Af = *reinterpret_cast<const bf16x8*>(
                    &s_Wa[kh*PBSA + (((eK << 8) + (n16 << 4) + vh) ^ ((eK & 7) << 3))]);
                const bf16x8 Bf = *reinterpret_cast<const bf16x8*>(
                    &s_tB[kh*PBSB + ((eK*ESB + (n16 << 4) + vh) ^ ((eK & 3) << 3))]);
                D[ee] = __builtin_amdgcn_mfma_f32_16x16x32_bf16(Af, Bf, D[ee], 0, 0, 0);
            }
        }
        __syncthreads();   // WAR: next K-block rewrites s_Wa / s_tB
    }

    // epilogue: D[row=w=q*4+r, col=oflat=n16] -> msg[e][oflat*16 + w] as bf16,
    // short4 (8B) stores; halves the msg round-trip vs fp32.
    if (n16 < 9) {
        #pragma unroll
        for (int ee = 0; ee < 4; ++ee) {
            const int eg = blockIdx.x * EPB + 4*wv + ee;
            if (eg < nE) {
                unsigned short* mp = msg + (size_t)eg * 144 + n16*16 + q*4;
                short4 pk;
                pk.x = (short)to_bf16(D[ee][0]); pk.y = (short)to_bf16(D[ee][1]);
                pk.z = (short)to_bf16(D[ee][2]); pk.w = (short)to_bf16(D[ee][3]);
                *reinterpret_cast<short4*>(mp) = pk;
            }
        }
    }
}

// ---------------- Phase B: node gather-reduce (no atomics, bf16 msg) ----------------
__global__ __launch_bounds__(BLK)
void se3_gather(const unsigned short* __restrict__ msg, const int* __restrict__ off,
                const int* __restrict__ eidx, const float* __restrict__ Nn,
                float* __restrict__ Out, const int nN)
{
    const int l = threadIdx.x & 15;
    const int g = threadIdx.x >> 4;
    const int n = blockIdx.x * 16 + g;
    if (n >= nN) return;

    const int i0 = off[n], i1 = off[n + 1];
    float s[9];
    #pragma unroll
    for (int j = 0; j < 9; ++j) s[j] = 0.f;

    for (int idx = i0; idx < i1; ++idx) {
        const int eid = eidx[idx];
        const unsigned short* m = msg + (size_t)eid * 144 + l;
        #pragma unroll
        for (int j = 0; j < 9; ++j) s[j] += bf2f(m[j * 16]);
    }

    const float nn = Nn[n];
    float* orow = Out + (size_t)n * 144;
    orow[l] = s[0] * nn;
    #pragma unroll
    for (int o = 0; o < 3; ++o) orow[16 + l*3 + o] = s[1+o] * nn;
    #pragma unroll
    for (int o = 0; o < 5; ++o) orow[64 + l*5 + o] = s[4+o] * nn;
}

// ---------------- CSR build (by destination) ----------------
__global__ void k_scan(int* __restrict__ cur, int* __restrict__ off, int N) {
    __shared__ int part[BLK];
    const int t = threadIdx.x;
    const int K = (N + BLK - 1) / BLK;
    const int i0 = t * K, i1 = min(i0 + K, N);
    int s = 0;
    for (int i = i0; i < i1; ++i) s += cur[i];
    part[t] = s;
    __syncthreads();
    if (t == 0) {
        int a = 0;
        for (int j = 0; j < BLK; ++j) { int v = part[j]; part[j] = a; a += v; }
        off[N] = a;
    }
    __syncthreads();
    int a = part[t];
    for (int i = i0; i < i1; ++i) {
        int v = cur[i];
        off[i] = a;
        cur[i] = a;       // reuse as scatter cursor
        a += v;
    }
}

__global__ void k_scatter(const int* __restrict__ Ma, int* __restrict__ cur,
                          int* __restrict__ eidx, int E) {
    int e = blockIdx.x * blockDim.x + threadIdx.x;
    if (e < E) {
        int pos = atomicAdd(&cur[Ma[e]], 1);
        eidx[pos] = e;
    }
}

extern "C" void kernel_launch(void* const* d_in, const int* in_sizes, int n_in,
                              void* d_out, int out_size, void* d_ws, size_t ws_size,
                              hipStream_t stream) {
    const float* F   = (const float*)d_in[0];
    const float* R   = (const float*)d_in[1];
    const float* Ys  = (const float*)d_in[2];
    const float* Rad = (const float*)d_in[3];
    const float* cg  = (const float*)d_in[4];
    const float* Nn  = (const float*)d_in[5];
    const int*   Ma  = (const int*)d_in[6];
    const int*   Mb  = (const int*)d_in[7];
    float* Out = (float*)d_out;

    const int nE = in_sizes[6];   // edges
    const int nN = in_sizes[5];   // nodes

    // ws layout (float units): [cur nN][off nN+1][eidx nE][pad]
    //   [msg nE*144 bf16 = nE*72 f32][pad][Rt NP*16*64*8 bf16]
    int* wsI  = (int*)d_ws;
    int* cur  = wsI;
    int* off  = wsI + nN;
    int* eidx = wsI + 2*nN + 1;
    size_t msgOff = ((size_t)(2*nN + 1 + nE) + 63) & ~(size_t)63;
    unsigned short* msg16 = (unsigned short*)((float*)d_ws + msgOff);
    size_t rtOff = ((msgOff + (size_t)nE * 72) + 63) & ~(size_t)63;
    unsigned short* Rt = (unsigned short*)((float*)d_ws + rtOff);

    const int RTB = (NP * 16 * 64 * 8) / BLK;          // 608
    const int CNT = (nE + BLK - 1) / BLK;

    hipMemsetAsync(cur, 0, (size_t)nN * sizeof(int), stream);
    k_rtcount<<<RTB + CNT, BLK, 0, stream>>>(R, Rt, Ma, cur, nE);
    k_scan   <<<1, BLK, 0, stream>>>(cur, off, nN);
    k_scatter<<<CNT, BLK, 0, stream>>>(Ma, cur, eidx, nE);

    se3_msg   <<<(nE + EPB - 1) / EPB, BLK, 0, stream>>>(F, Ys, Rad, cg, Rt, Mb, msg16, nE);
    se3_gather<<<(nN + 15) / 16, BLK, 0, stream>>>(msg16, off, eidx, Nn, Out, nN);
}